// Round 3
// baseline (35.949 us; speedup 1.0000x reference)
//
#include <hip/hip_runtime.h>

#define BDIM 512
#define NLEN 9000
#define NV4  2250        // NLEN / 4 (exact)
#define KMAX 5           // ceil(NV4 / BDIM)
#define NWAVE (BDIM / 64)
#define RPB  8           // rows per block (persistent, software-pipelined)

// Execution barrier that makes this wave's LDS writes visible WITHOUT draining
// vmcnt: unlike __syncthreads() (which hipcc lowers to s_waitcnt vmcnt(0)
// lgkmcnt(0) + s_barrier), this keeps the cross-row global prefetch loads in
// flight across the barrier. The compiler still emits counted vmcnt waits at
// the first USE of each prefetched register. ("memory" clobber = compiler-level
// fence so no LDS/global C access is reordered across the barrier.)
__device__ __forceinline__ void barrier_lds_only() {
    asm volatile("s_waitcnt lgkmcnt(0)" ::: "memory");
    __builtin_amdgcn_s_barrier();
    asm volatile("" ::: "memory");
}

__global__ __launch_bounds__(BDIM, 4) void PeakbasedDetector_43542378447356_kernel(
    const float* __restrict__ sig,
    const float* __restrict__ times,
    float* __restrict__ out,
    int nrows)
{
    // Boundary values only, double-buffered across pipelined rows:
    // chunk i stores x at bnd[buf][2+2i], w at bnd[buf][3+2i].
    // bnd[buf][1] / bnd[buf][2+2*NV4] are +INF sentinels (endpoints never peaks):
    //   L(chunk i) = bnd[buf][1+2i]  (w of chunk i-1)
    //   R(chunk i) = bnd[buf][4+2i]  (x of chunk i+1)
    __shared__ float bnd[2][2 * NV4 + 4];              // 36.0 KB
    __shared__ float red_mn[NWAVE], red_mx[NWAVE];
    __shared__ int   red_c[NWAVE], red_fi[NWAVE], red_li[NWAVE];

    const int tid  = threadIdx.x;
    const int lane = tid & 63;
    const int wid  = tid >> 6;
    const int row0 = blockIdx.x * RPB;

    if (tid == 0) {
        bnd[0][1]           = 3.402823466e+38f;
        bnd[0][2 + 2 * NV4] = 3.402823466e+38f;
        bnd[1][1]           = 3.402823466e+38f;
        bnd[1][2 + 2 * NV4] = 3.402823466e+38f;
    }   // ordered before first use by barrier1 of row 0

    // ---- prologue: issue loads for row0 (coalesced float4)
    float4 v[KMAX];
    {
        const float4* srow = (const float4*)(sig + (size_t)row0 * NLEN);
        #pragma unroll
        for (int k = 0; k < KMAX; ++k) {
            int i4 = tid + k * BDIM;
            if (i4 < NV4) v[k] = srow[i4];
        }
    }

    int cur = 0;
    for (int r = 0; r < RPB; ++r) {
        const int row = row0 + r;
        if (row >= nrows) break;                       // block-uniform

        // ---- A: min/max over v (counted vmcnt waits per chunk); stash boundaries
        float mn =  3.402823466e+38f;
        float mx = -3.402823466e+38f;
        #pragma unroll
        for (int k = 0; k < KMAX; ++k) {
            int i4 = tid + k * BDIM;
            if (i4 < NV4) {
                *(float2*)&bnd[cur][2 + 2 * i4] = make_float2(v[k].x, v[k].w);
                // linear chains -> v_min3/v_max3 fusion
                mn = fminf(fminf(fminf(fminf(mn, v[k].x), v[k].y), v[k].z), v[k].w);
                mx = fmaxf(fmaxf(fmaxf(fmaxf(mx, v[k].x), v[k].y), v[k].z), v[k].w);
            }
        }
        #pragma unroll
        for (int off = 32; off > 0; off >>= 1) {
            mn = fminf(mn, __shfl_down(mn, off, 64));
            mx = fmaxf(mx, __shfl_down(mx, off, 64));
        }
        if (lane == 0) { red_mn[wid] = mn; red_mx[wid] = mx; }
        barrier_lds_only();                            // barrier1: bnd[cur] + red_mn/mx
        mn = red_mn[0]; mx = red_mx[0];
        #pragma unroll
        for (int w = 1; w < NWAVE; ++w) {
            mn = fminf(mn, red_mn[w]);
            mx = fmaxf(mx, red_mx[w]);
        }
        // norm >= 0.3  <=>  sig >= mn + 0.3*d (monotone; same as verified baseline)
        const float thr = mn + 0.3f * ((mx - mn) + 1e-8f);

        // ---- B: detect row r from registers; PREFETCH row r+1 into v[k] as we go.
        // These loads now survive barrier2 + epilogue + barrier1(r+1): the memory
        // pipe stays busy while this block computes (anti-convoy).
        const bool more = (r + 1 < RPB) && (row + 1 < nrows);   // block-uniform
        const float4* nrow = (const float4*)(sig + (size_t)(row + 1) * NLEN);
        int cnt = 0, mini = NLEN, maxi = -1;
        #pragma unroll
        for (int k = 0; k < KMAX; ++k) {
            int i4 = tid + k * BDIM;
            if (i4 < NV4) {
                const float a = v[k].x, b = v[k].y, c = v[k].z, e = v[k].w;
                if (more) v[k] = nrow[i4];             // issue next-row load now
                const float L = bnd[cur][1 + 2 * i4];
                const float R = bnd[cur][4 + 2 * i4];
                const int base = i4 * 4;
                // a>=b && a>=thr  <=>  a >= fmax(b,thr)
                const bool pa = (a > L) & (a >= fmaxf(b, thr));
                const bool pb = (b > a) & (b >= fmaxf(c, thr));
                const bool pc = (c > b) & (c >= fmaxf(e, thr));
                const bool pe = (e > c) & (e >= fmaxf(R, thr));
                cnt += pa + pb + pc + pe;
                mini = pa ? min(mini, base    ) : mini;
                mini = pb ? min(mini, base + 1) : mini;
                mini = pc ? min(mini, base + 2) : mini;
                mini = pe ? min(mini, base + 3) : mini;
                maxi = pa ? base     : maxi;           // ascending scan: overwrite = max
                maxi = pb ? base + 1 : maxi;
                maxi = pc ? base + 2 : maxi;
                maxi = pe ? base + 3 : maxi;
            }
        }

        // ---- reduce {count, first, last}
        #pragma unroll
        for (int off = 32; off > 0; off >>= 1) {
            cnt  += __shfl_down(cnt, off, 64);
            mini  = min(mini, __shfl_down(mini, off, 64));
            maxi  = max(maxi, __shfl_down(maxi, off, 64));
        }
        if (lane == 0) { red_c[wid] = cnt; red_fi[wid] = mini; red_li[wid] = maxi; }
        barrier_lds_only();                            // barrier2 (prefetch stays in flight)

        // ---- epilogue for row r (tid0 only; others run ahead into A(r+1))
        if (tid == 0) {
            int c = 0, fi = NLEN, li = -1;
            #pragma unroll
            for (int w = 0; w < NWAVE; ++w) {
                c += red_c[w];
                fi = min(fi, red_fi[w]);
                li = max(li, red_li[w]);
            }
            float res = 0.0f;
            if (c >= 2) {
                const float* trow = times + (size_t)row * NLEN;
                float tf = trow[fi] * 1000.0f;
                float tl = trow[li] * 1000.0f;
                res = (tl - tf) / (float)(c - 1);
            }
            out[row] = res;
        }
        cur ^= 1;
        // hazard walk (same as verified round-2 structure; barriers are at the
        // same program points, only the vmcnt drain is removed — LDS ordering
        // needs lgkmcnt only): bnd[cur^1] rewritten in A(r+2), fenced by
        // barrier1(r+1)+barrier2(r+1); red_mn rewritten in A(r+1) after
        // barrier2(r); red_c rewritten end of B(r+1), after barrier1(r+1)
        // which tid0 joins only after its epilogue read.
    }
}

extern "C" void kernel_launch(void* const* d_in, const int* in_sizes, int n_in,
                              void* d_out, int out_size, void* d_ws, size_t ws_size,
                              hipStream_t stream) {
    const float* sig   = (const float*)d_in[0];
    const float* times = (const float*)d_in[1];
    float* out = (float*)d_out;
    const int B = out_size;                  // 4096 rows
    const int grid = (B + RPB - 1) / RPB;    // 512 blocks, persistent
    PeakbasedDetector_43542378447356_kernel<<<grid, BDIM, 0, stream>>>(sig, times, out, B);
}

// Round 4
// 29.539 us; speedup vs baseline: 1.2170x; 1.2170x over previous
//
#include <hip/hip_runtime.h>

#define BDIM  256
#define NLEN  9000
#define EPT   36          // elements per thread, contiguous: 250 * 36 = 9000
#define NACT  250         // active threads per row
#define NWAVE (BDIM / 64)
#define POSINF ( 3.402823466e+38f)
#define NEGINF (-3.402823466e+38f)

__global__ __launch_bounds__(BDIM, 8) void PeakbasedDetector_43542378447356_kernel(
    const float* __restrict__ sig,
    const float* __restrict__ times,
    float* __restrict__ out)
{
    // LDS: only cross-wave reduction scalars (80 B). No data staging at all.
    __shared__ float red_mn[NWAVE], red_mx[NWAVE];
    __shared__ int   red_c[NWAVE], red_fi[NWAVE], red_li[NWAVE];

    const int row  = blockIdx.x;
    const int tid  = threadIdx.x;
    const int lane = tid & 63;
    const int wid  = tid >> 6;
    const float* srow = sig + (size_t)row * NLEN;
    const bool active = (tid < NACT);

    // ---- phase 1 (everything here hides under this wave's own load latency) ----
    // Thread t owns elements [t*36, t*36+36): 9 aligned float4 loads + 2 scalar
    // neighbor loads (L = elem t*36-1, R = elem t*36+36; same cache lines as the
    // bulk stream). All 35 interior adjacencies are register-register.
    float s[EPT];
    float L = POSINF, R = POSINF;          // +INF sentinels: row endpoints never peaks
    float mn = POSINF, mx = NEGINF;

    if (active) {
        const float4* p4 = (const float4*)(srow + tid * EPT);   // 144B-aligned
        #pragma unroll
        for (int k = 0; k < EPT / 4; ++k)
            *(float4*)&s[4 * k] = p4[k];
        if (tid > 0)        L = srow[tid * EPT - 1];
        if (tid < NACT - 1) R = srow[tid * EPT + EPT];

        #pragma unroll
        for (int i = 0; i < EPT; ++i) {
            mn = fminf(mn, s[i]);
            mx = fmaxf(mx, s[i]);
        }

        // threshold-INDEPENDENT local-max pass, in place:
        // peak candidate <=> s[i] > s[i-1] && s[i] >= s[i+1] (ref semantics).
        // Substitute s[i] = candidate ? s[i] : -INF; the post-barrier phase
        // then needs no neighbor data at all.
        float prev = L;
        #pragma unroll
        for (int i = 0; i < EPT; ++i) {
            const float cur = s[i];
            const float nxt = (i < EPT - 1) ? s[i + 1] : R;
            const bool  p   = (cur > prev) & (cur >= nxt);
            s[i] = p ? cur : NEGINF;
            prev = cur;
        }
    }

    // ---- block min/max reduction ----
    #pragma unroll
    for (int off = 32; off > 0; off >>= 1) {
        mn = fminf(mn, __shfl_down(mn, off, 64));
        mx = fmaxf(mx, __shfl_down(mx, off, 64));
    }
    if (lane == 0) { red_mn[wid] = mn; red_mx[wid] = mx; }
    __syncthreads();
    mn = fminf(fminf(red_mn[0], red_mn[1]), fminf(red_mn[2], red_mn[3]));
    mx = fmaxf(fmaxf(red_mx[0], red_mx[1]), fmaxf(red_mx[2], red_mx[3]));
    // norm >= 0.3  <=>  sig >= mn + 0.3*d (monotone; same algebra as verified rounds)
    const float thr = mn + 0.3f * ((mx - mn) + 1e-8f);

    // ---- phase 2 (tiny): threshold scan over substituted values ----
    // -INF never passes; indices are thread-contiguous so fi/li are local [0,36).
    int cnt = 0, fi = 64, li = -1;
    if (active) {
        #pragma unroll
        for (int i = 0; i < EPT; ++i) {
            const bool p = (s[i] >= thr);
            cnt += p;
            fi = min(fi, p ? i : 64);      // first hit (i ascending)
            li = p ? i : li;               // last hit (overwrite)
        }
    }
    int gmi = (li >= 0) ? tid * EPT + fi : (1 << 30);
    int gma = (li >= 0) ? tid * EPT + li : -1;

    // ---- block reduce {count, first, last} ----
    #pragma unroll
    for (int off = 32; off > 0; off >>= 1) {
        cnt += __shfl_down(cnt, off, 64);
        gmi  = min(gmi, __shfl_down(gmi, off, 64));
        gma  = max(gma, __shfl_down(gma, off, 64));
    }
    if (lane == 0) { red_c[wid] = cnt; red_fi[wid] = gmi; red_li[wid] = gma; }
    __syncthreads();

    // ---- epilogue ----
    if (tid == 0) {
        int c  = red_c[0] + red_c[1] + red_c[2] + red_c[3];
        int f  = min(min(red_fi[0], red_fi[1]), min(red_fi[2], red_fi[3]));
        int l  = max(max(red_li[0], red_li[1]), max(red_li[2], red_li[3]));
        float r = 0.0f;
        if (c >= 2) {
            const float* trow = times + (size_t)row * NLEN;
            float tf = trow[f] * 1000.0f;
            float tl = trow[l] * 1000.0f;
            r = (tl - tf) / (float)(c - 1);
        }
        out[row] = r;
    }
}

extern "C" void kernel_launch(void* const* d_in, const int* in_sizes, int n_in,
                              void* d_out, int out_size, void* d_ws, size_t ws_size,
                              hipStream_t stream) {
    const float* sig   = (const float*)d_in[0];
    const float* times = (const float*)d_in[1];
    float* out = (float*)d_out;
    const int B = out_size;   // 4096 rows
    PeakbasedDetector_43542378447356_kernel<<<B, BDIM, 0, stream>>>(sig, times, out);
}